// Round 7
// baseline (125.199 us; speedup 1.0000x reference)
//
#include <hip/hip_runtime.h>
#include <hip/hip_fp16.h>

typedef _Float16 f16;
typedef f16 f16x4 __attribute__((ext_vector_type(4)));
typedef f16 f16x8 __attribute__((ext_vector_type(8)));
typedef float f32x4 __attribute__((ext_vector_type(4)));

#define NN 1024

// workspace layout (bytes) — img2 identical to rounds 5/6 (verified)
// img2: f16 [20][8192] — B-operand images in FRAGMENT-LINEAR order:
//   per (chunk c, wn half): 4096 f16 = [nt:4][ks:2][lane:64][8 f16],
//   element = B[n = wn*64+nt*16+lm][k = ks*32+q*8+s], lane = q*16+lm.
//   chunks 0..15 : W0^T j-chunks; 16,17 : W1 k-halves; 18,19 : W2 k-halves
#define IMG2_OFF  0
#define W8_OFF    327680                 // f32 [128] : W0[8][:] (norm row)
#define BIAS0_OFF 328192                 // f32 [32][128] : b0 + u[b] @ W0[0:8]

__global__ __launch_bounds__(256) void prep_kernel(
    const float* __restrict__ u,  const float* __restrict__ W0,
    const float* __restrict__ b0, const float* __restrict__ W1,
    const float* __restrict__ W2,
    f16* __restrict__ img2, float* __restrict__ w8v, float* __restrict__ bias0,
    float* __restrict__ outp)
{
    const int t = threadIdx.x;
    const int blk = blockIdx.x;
    if (blk < 160) {
        int flat = blk * 1024 + t * 4;
        int c   = flat >> 13;
        int rem = flat & 8191;
        int s0  = rem & 7;              // 0 or 4
        int lm  = (rem >> 3) & 15;
        int q   = (rem >> 7) & 3;
        int ks  = (rem >> 9) & 1;
        int nt  = (rem >> 10) & 3;
        int wn  = (rem >> 12) & 1;
        int n = wn * 64 + nt * 16 + lm;
        f16x4 v;
#pragma unroll
        for (int e = 0; e < 4; ++e) {
            int k = ks * 32 + q * 8 + s0 + e;
            float val;
            if (c < 16)       val = W0[(9 + c * 64 + k) * 128 + n];
            else if (c < 18)  val = W1[((c - 16) * 64 + k) * 128 + n];
            else              val = W2[((c - 18) * 64 + k) * 128 + n];
            v[e] = (f16)val;
        }
        *(f16x4*)&img2[flat] = v;
    } else if (blk < 176) {
        int idx = (blk - 160) * 256 + t;
        int b = idx >> 7, h = idx & 127;
        float s = b0[h];
#pragma unroll
        for (int g = 0; g < 8; ++g) s += u[b * 8 + g] * W0[g * 128 + h];
        bias0[idx] = s;
    } else if (blk == 176) {
        if (t < 128) w8v[t] = W0[8 * 128 + t];
    } else {
        int idx = (blk - 177) * 1024 + t * 4;
        if (idx < 12288) { float4 z = {0.f, 0.f, 0.f, 0.f}; *(float4*)&outp[idx] = z; }
    }
}

// 32-row i-tile, 1024 blocks. WHOLE 32x1024 D-tile materialized in LDS once
// (phase 1, 1 barrier), then the K=1024 layer-0 GEMM runs BARRIER-FREE
// (phase 2): A from read-only LDS, B direct from L2 (img2 fragment images).
__global__ __launch_bounds__(256, 2) void fused_kernel(
    const float* __restrict__ x, const float* __restrict__ b1p,
    const float* __restrict__ b2p, const f16* __restrict__ img2,
    const float* __restrict__ w8v, const float* __restrict__ bias0,
    float* __restrict__ outp)
{
    // 74.1 KB static LDS -> 2 blocks/CU (LDS-capped)
    __shared__ __align__(16) f16 Dsh[32 * 1024];   // 64 KB, XOR-swizzled rows
    __shared__ __align__(16) f16 Hx[32 * 136];     // 8.7 KB: xj staging (phase 1),
                                                   // then h0/h1 (+8-padded rows)
    __shared__ __align__(16) float xi[32 * 4];
    __shared__ float normv[32];
    __shared__ float biass[128];
    __shared__ float w8s[128];

    const int t = threadIdx.x;
    const int b = blockIdx.x >> 5;
    const int i0 = (blockIdx.x & 31) * 32;

    // ---- stage all 1024 x-rows as f16x4 (w=0) into Hx-as-xj ----
    {
        const float* xb = x + (size_t)b * NN * 3;
        float4 v0 = *(const float4*)(xb + t * 12);
        float4 v1 = *(const float4*)(xb + t * 12 + 4);
        float4 v2 = *(const float4*)(xb + t * 12 + 8);
        f16x4 r0; r0[0] = (f16)v0.x; r0[1] = (f16)v0.y; r0[2] = (f16)v0.z; r0[3] = (f16)0;
        f16x4 r1; r1[0] = (f16)v0.w; r1[1] = (f16)v1.x; r1[2] = (f16)v1.y; r1[3] = (f16)0;
        f16x4 r2; r2[0] = (f16)v1.z; r2[1] = (f16)v1.w; r2[2] = (f16)v2.x; r2[3] = (f16)0;
        f16x4 r3; r3[0] = (f16)v2.y; r3[1] = (f16)v2.z; r3[2] = (f16)v2.w; r3[3] = (f16)0;
        *(f16x4*)&Hx[(t * 4 + 0) * 4] = r0;
        *(f16x4*)&Hx[(t * 4 + 1) * 4] = r1;
        *(f16x4*)&Hx[(t * 4 + 2) * 4] = r2;
        *(f16x4*)&Hx[(t * 4 + 3) * 4] = r3;
    }
    if (t < 96) {
        int i = t / 3, d = t - i * 3;
        xi[i * 4 + d] = x[(size_t)(b * NN + i0 + i) * 3 + d];
    }
    if (t >= 128) { biass[t - 128] = bias0[b * 128 + (t - 128)]; w8s[t - 128] = w8v[t - 128]; }
    __syncthreads();
    if (t < 32) {
        float a0 = xi[t * 4], a1 = xi[t * 4 + 1], a2 = xi[t * 4 + 2];
        normv[t] = __builtin_amdgcn_sqrtf(a0 * a0 + a1 * a1 + a2 * a2);
    }

    const int lane = t & 63, wv = t >> 6;
    const int wm = wv >> 1, wn = wv & 1;     // wave tile: 16 i x 64 h
    const int lm = lane & 15, q = lane >> 4;

    // xi B-fragments for dot-MFMA (16x16x16, layout verified R1-R6):
    f16x4 bi[2];
#pragma unroll
    for (int it = 0; it < 2; ++it) {
        f16x4 v; v[0] = (f16)0; v[1] = (f16)0; v[2] = (f16)0; v[3] = (f16)0;
        if (q == 0) {
            int ii = it * 16 + lm;
            v[0] = (f16)xi[ii * 4];
            v[1] = (f16)xi[ii * 4 + 1];
            v[2] = (f16)xi[ii * 4 + 2];
        }
        bi[it] = v;
    }

    f32x4 acc[4];
    auto zero_acc = [&]() {
#pragma unroll
        for (int nt = 0; nt < 4; ++nt)
#pragma unroll
            for (int e = 0; e < 4; ++e) acc[nt][e] = 0.f;
    };
    zero_acc();

    // ---- phase 1: generate the WHOLE 32x1024 D-tile (no inter-chunk deps) ----
    // lane holds D[j = jc*64 + wv*16 + q*4 + r][i = it*16 + lm]
#pragma unroll 4
    for (int jc = 0; jc < 16; ++jc) {
        f16x4 ajv; ajv[0] = (f16)0; ajv[1] = (f16)0; ajv[2] = (f16)0; ajv[3] = (f16)0;
        if (q == 0)
            ajv = *(const f16x4*)&Hx[(jc * 64 + wv * 16 + lm) * 4];
#pragma unroll
        for (int it = 0; it < 2; ++it) {
            f32x4 z; z[0] = 0.f; z[1] = 0.f; z[2] = 0.f; z[3] = 0.f;
            f32x4 cg = __builtin_amdgcn_mfma_f32_16x16x16f16(ajv, bi[it], z, 0, 0, 0);
            f16x4 dv;
#pragma unroll
            for (int r = 0; r < 4; ++r)
                dv[r] = (f16)__builtin_amdgcn_sqrtf(fmaxf(cg[r], 0.f));
            int row = it * 16 + lm;                    // i (0..31)
            int col = jc * 64 + wv * 16 + q * 4;       // j (0..1023), 4-aligned
            int addr = row * 1024 + (((col & ~7) ^ ((row & 7) << 3)) | (col & 7));
            *(f16x4*)&Dsh[addr] = dv;
        }
    }
    __syncthreads();

    // ---- phase 2: layer-0 GEMM, K=1024, BARRIER-FREE ----
    // A row = wm*16+lm from Dsh (swizzled, stride 1024); B direct from img2.
#pragma unroll 4
    for (int c = 0; c < 16; ++c) {
        const f16* wb = img2 + (size_t)(c * 2 + wn) * 4096 + lane * 8;
        f16x8 bf[4][2];
#pragma unroll
        for (int nt = 0; nt < 4; ++nt)
#pragma unroll
            for (int ks = 0; ks < 2; ++ks)
                bf[nt][ks] = *(const f16x8*)(wb + (nt * 2 + ks) * 512);
        f16x8 af[2];
        {
            int row = wm * 16 + lm;
#pragma unroll
            for (int ks = 0; ks < 2; ++ks) {
                int col = c * 64 + ks * 32 + q * 8;     // 8-aligned
                af[ks] = *(const f16x8*)(Dsh + row * 1024 + (col ^ ((row & 7) << 3)));
            }
        }
#pragma unroll
        for (int ks = 0; ks < 2; ++ks)
#pragma unroll
            for (int nt = 0; nt < 4; ++nt)
                acc[nt] = __builtin_amdgcn_mfma_f32_16x16x32_f16(
                    af[ks], bf[nt][ks], acc[nt], 0, 0, 0);
    }

    // ---- epilogue 0: h0 = leaky(acc + bias + norm*w8) -> Hx (padded 136) ----
    // lane holds C[i = wm*16 + q*4 + r][h = wn*64 + nt*16 + lm]
#pragma unroll
    for (int nt = 0; nt < 4; ++nt) {
        const int h = wn * 64 + nt * 16 + lm;
        const float bh = biass[h], w8h = w8s[h];
#pragma unroll
        for (int r = 0; r < 4; ++r) {
            int i = wm * 16 + q * 4 + r;
            float val = acc[nt][r] + bh + normv[i] * w8h;
            val = val > 0.f ? val : 0.01f * val;
            Hx[i * 136 + h] = (f16)val;
        }
    }
    __syncthreads();

    // ---- layer 1: A = h0 from Hx (stride 136, no swizzle), B = chunks 16,17 ----
    zero_acc();
#pragma unroll
    for (int hb = 0; hb < 2; ++hb) {
        const f16* wb = img2 + (size_t)((16 + hb) * 2 + wn) * 4096 + lane * 8;
        f16x8 bf[4][2];
#pragma unroll
        for (int nt = 0; nt < 4; ++nt)
#pragma unroll
            for (int ks = 0; ks < 2; ++ks)
                bf[nt][ks] = *(const f16x8*)(wb + (nt * 2 + ks) * 512);
        f16x8 af[2];
        {
            int row = wm * 16 + lm;
#pragma unroll
            for (int ks = 0; ks < 2; ++ks)
                af[ks] = *(const f16x8*)(Hx + row * 136 + hb * 64 + ks * 32 + q * 8);
        }
#pragma unroll
        for (int ks = 0; ks < 2; ++ks)
#pragma unroll
            for (int nt = 0; nt < 4; ++nt)
                acc[nt] = __builtin_amdgcn_mfma_f32_16x16x32_f16(
                    af[ks], bf[nt][ks], acc[nt], 0, 0, 0);
    }
    __syncthreads();

    // ---- epilogue 1: h1 = leaky(acc + b1) -> Hx ----
#pragma unroll
    for (int nt = 0; nt < 4; ++nt) {
        const int h = wn * 64 + nt * 16 + lm;
        const float bh = b1p[h];
#pragma unroll
        for (int r = 0; r < 4; ++r) {
            int i = wm * 16 + q * 4 + r;
            float val = acc[nt][r] + bh;
            val = val > 0.f ? val : 0.01f * val;
            Hx[i * 136 + h] = (f16)val;
        }
    }
    __syncthreads();

    // ---- layer 2: B = chunks 18,19 ----
    zero_acc();
#pragma unroll
    for (int hb = 0; hb < 2; ++hb) {
        const f16* wb = img2 + (size_t)((18 + hb) * 2 + wn) * 4096 + lane * 8;
        f16x8 bf[4][2];
#pragma unroll
        for (int nt = 0; nt < 4; ++nt)
#pragma unroll
            for (int ks = 0; ks < 2; ++ks)
                bf[nt][ks] = *(const f16x8*)(wb + (nt * 2 + ks) * 512);
        f16x8 af[2];
        {
            int row = wm * 16 + lm;
#pragma unroll
            for (int ks = 0; ks < 2; ++ks)
                af[ks] = *(const f16x8*)(Hx + row * 136 + hb * 64 + ks * 32 + q * 8);
        }
#pragma unroll
        for (int ks = 0; ks < 2; ++ks)
#pragma unroll
            for (int nt = 0; nt < 4; ++nt)
                acc[nt] = __builtin_amdgcn_mfma_f32_16x16x32_f16(
                    af[ks], bf[nt][ks], acc[nt], 0, 0, 0);
    }

    // ---- contraction: out[b,o,d] += sum_i (fk+b2)*x_i / N ----
    float p[4][3];
#pragma unroll
    for (int nt = 0; nt < 4; ++nt)
#pragma unroll
        for (int d = 0; d < 3; ++d) p[nt][d] = 0.f;
    float bo[4];
#pragma unroll
    for (int nt = 0; nt < 4; ++nt) bo[nt] = b2p[wn * 64 + nt * 16 + lm];
#pragma unroll
    for (int r = 0; r < 4; ++r) {
        int i = wm * 16 + q * 4 + r;
        float x0 = xi[i * 4], x1 = xi[i * 4 + 1], x2 = xi[i * 4 + 2];
#pragma unroll
        for (int nt = 0; nt < 4; ++nt) {
            float fkv = acc[nt][r] + bo[nt];
            p[nt][0] = fmaf(fkv, x0, p[nt][0]);
            p[nt][1] = fmaf(fkv, x1, p[nt][1]);
            p[nt][2] = fmaf(fkv, x2, p[nt][2]);
        }
    }
#pragma unroll
    for (int nt = 0; nt < 4; ++nt)
#pragma unroll
        for (int d = 0; d < 3; ++d) {
            float s = p[nt][d];
            s += __shfl_xor(s, 16);
            s += __shfl_xor(s, 32);
            if (q == 0) {
                int o = wn * 64 + nt * 16 + lm;
                atomicAdd(&outp[(b * 128 + o) * 3 + d], s * (1.0f / 1024.0f));
            }
        }
}

extern "C" void kernel_launch(void* const* d_in, const int* in_sizes, int n_in,
                              void* d_out, int out_size, void* d_ws, size_t ws_size,
                              hipStream_t stream) {
    const float* x  = (const float*)d_in[0];
    const float* u  = (const float*)d_in[1];
    const float* W0 = (const float*)d_in[2];
    const float* b0 = (const float*)d_in[3];
    const float* W1 = (const float*)d_in[4];
    const float* b1 = (const float*)d_in[5];
    const float* W2 = (const float*)d_in[6];
    const float* b2 = (const float*)d_in[7];

    char* ws = (char*)d_ws;
    f16*   img2  = (f16*)(ws + IMG2_OFF);
    float* w8v   = (float*)(ws + W8_OFF);
    float* bias0 = (float*)(ws + BIAS0_OFF);
    float* out   = (float*)d_out;

    prep_kernel<<<189, 256, 0, stream>>>(u, W0, b0, W1, W2, img2, w8v, bias0, out);
    fused_kernel<<<1024, 256, 0, stream>>>(x, b1, b2, img2, w8v, bias0, out);
}

// Round 8
// 85.441 us; speedup vs baseline: 1.4653x; 1.4653x over previous
//
#include <hip/hip_runtime.h>
#include <hip/hip_fp16.h>

typedef _Float16 f16;
typedef f16 f16x4 __attribute__((ext_vector_type(4)));
typedef f16 f16x8 __attribute__((ext_vector_type(8)));
typedef float f32x4 __attribute__((ext_vector_type(4)));

#define NN 1024

// workspace layout (bytes) — img2 IDENTICAL to rounds 5-7 (verified)
// img2: f16 [20][8192] — B-operand images in FRAGMENT-LINEAR order:
//   per (chunk c, half in {0,1}): 4096 f16 = [nt:4][ks:2][lane:64][8 f16],
//   element = B[n = half*64+nt*16+lm][k = ks*32+q*8+s], lane = q*16+lm.
//   chunks 0..15 : W0^T j-chunks; 16,17 : W1 k-halves; 18,19 : W2 k-halves
#define IMG2_OFF  0
#define W8_OFF    327680                 // f32 [128] : W0[8][:] (norm row)
#define BIAS0_OFF 328192                 // f32 [32][128] : b0 + u[b] @ W0[0:8]

__global__ __launch_bounds__(256) void prep_kernel(
    const float* __restrict__ u,  const float* __restrict__ W0,
    const float* __restrict__ b0, const float* __restrict__ W1,
    const float* __restrict__ W2,
    f16* __restrict__ img2, float* __restrict__ w8v, float* __restrict__ bias0,
    float* __restrict__ outp)
{
    const int t = threadIdx.x;
    const int blk = blockIdx.x;
    if (blk < 160) {
        int flat = blk * 1024 + t * 4;
        int c   = flat >> 13;
        int rem = flat & 8191;
        int s0  = rem & 7;              // 0 or 4
        int lm  = (rem >> 3) & 15;
        int q   = (rem >> 7) & 3;
        int ks  = (rem >> 9) & 1;
        int nt  = (rem >> 10) & 3;
        int wn  = (rem >> 12) & 1;
        int n = wn * 64 + nt * 16 + lm;
        f16x4 v;
#pragma unroll
        for (int e = 0; e < 4; ++e) {
            int k = ks * 32 + q * 8 + s0 + e;
            float val;
            if (c < 16)       val = W0[(9 + c * 64 + k) * 128 + n];
            else if (c < 18)  val = W1[((c - 16) * 64 + k) * 128 + n];
            else              val = W2[((c - 18) * 64 + k) * 128 + n];
            v[e] = (f16)val;
        }
        *(f16x4*)&img2[flat] = v;
    } else if (blk < 176) {
        int idx = (blk - 160) * 256 + t;
        int b = idx >> 7, h = idx & 127;
        float s = b0[h];
#pragma unroll
        for (int g = 0; g < 8; ++g) s += u[b * 8 + g] * W0[g * 128 + h];
        bias0[idx] = s;
    } else if (blk == 176) {
        if (t < 128) w8v[t] = W0[8 * 128 + t];
    } else {
        int idx = (blk - 177) * 1024 + t * 4;
        if (idx < 12288) { float4 z = {0.f, 0.f, 0.f, 0.f}; *(float4*)&outp[idx] = z; }
    }
}

// Block = 64 i-rows x 128 h; 4 waves; wave tile = 64 i x 32 h (h-quarter wv).
// B-fragments direct from L2, software-pipelined ONE CHUNK AHEAD in registers.
// Grid 512 -> 2 blocks/CU, 8 waves/CU. B-traffic 128 MB total (half of R5).
__global__ __launch_bounds__(256, 2) void fused_kernel(
    const float* __restrict__ x, const float* __restrict__ b1p,
    const float* __restrict__ b2p, const f16* __restrict__ img2,
    const float* __restrict__ w8v, const float* __restrict__ bias0,
    float* __restrict__ outp)
{
    // 26.3 KB LDS
    __shared__ __align__(16) f16 Dsh[2][64 * 64];   // 16 KB D dbuf; later Hh[64][128]
    __shared__ __align__(16) f16 xjsh[1024 * 4];    // 8 KB: all x rows f16, [3]=0
    __shared__ __align__(16) float xi[64 * 4];
    __shared__ float normv[64];
    __shared__ float biass[128];
    __shared__ float w8s[128];

    const int t = threadIdx.x;
    const int b = blockIdx.x >> 4;
    const int i0 = (blockIdx.x & 15) * 64;

    const int lane = t & 63, wv = t >> 6;
    const int lm = lane & 15, q = lane >> 4;
    const int half = wv >> 1;           // img2 64-h half
    const int nbase = (wv & 1) * 2;     // nt offset inside the half
    f16* Hh = &Dsh[0][0];               // 64 x 128 swizzled h0/h1 buffer (16 KB)

    // ---- stage xjsh (all 1024 rows as f16x4, w=0) ----
    {
        const float* xb = x + (size_t)b * NN * 3;
        float4 v0 = *(const float4*)(xb + t * 12);
        float4 v1 = *(const float4*)(xb + t * 12 + 4);
        float4 v2 = *(const float4*)(xb + t * 12 + 8);
        f16x4 r0; r0[0] = (f16)v0.x; r0[1] = (f16)v0.y; r0[2] = (f16)v0.z; r0[3] = (f16)0;
        f16x4 r1; r1[0] = (f16)v0.w; r1[1] = (f16)v1.x; r1[2] = (f16)v1.y; r1[3] = (f16)0;
        f16x4 r2; r2[0] = (f16)v1.z; r2[1] = (f16)v1.w; r2[2] = (f16)v2.x; r2[3] = (f16)0;
        f16x4 r3; r3[0] = (f16)v2.y; r3[1] = (f16)v2.z; r3[2] = (f16)v2.w; r3[3] = (f16)0;
        *(f16x4*)&xjsh[(t * 4 + 0) * 4] = r0;
        *(f16x4*)&xjsh[(t * 4 + 1) * 4] = r1;
        *(f16x4*)&xjsh[(t * 4 + 2) * 4] = r2;
        *(f16x4*)&xjsh[(t * 4 + 3) * 4] = r3;
    }
    if (t < 192) {
        int i = t / 3, d = t - i * 3;
        xi[i * 4 + d] = x[(size_t)(b * NN + i0 + i) * 3 + d];
    }
    if (t < 128) { biass[t] = bias0[b * 128 + t]; w8s[t] = w8v[t]; }
    __syncthreads();
    if (t < 64) {
        float a0 = xi[t * 4], a1 = xi[t * 4 + 1], a2 = xi[t * 4 + 2];
        normv[t] = __builtin_amdgcn_sqrtf(a0 * a0 + a1 * a1 + a2 * a2);
    }

    // xi B-fragments for dot-MFMA (16x16x16, layout verified R1-R7):
    // lane(q==0,lm) holds coords of i = it*16+lm in k-slots 0..2.
    f16x4 bi[4];
#pragma unroll
    for (int it = 0; it < 4; ++it) {
        f16x4 v; v[0] = (f16)0; v[1] = (f16)0; v[2] = (f16)0; v[3] = (f16)0;
        if (q == 0) {
            int ii = it * 16 + lm;
            v[0] = (f16)xi[ii * 4];
            v[1] = (f16)xi[ii * 4 + 1];
            v[2] = (f16)xi[ii * 4 + 2];
        }
        bi[it] = v;
    }

    // dot-MFMA for chunk jc -> sqrt -> b64 stores into Dsh[buf]
    // (verbatim R1/R5 math: lane holds D[j = wv*16+q*4+r][i = it*16+lm])
    auto dotstore = [&](int jc, int buf) {
        f16x4 ajv; ajv[0] = (f16)0; ajv[1] = (f16)0; ajv[2] = (f16)0; ajv[3] = (f16)0;
        if (q == 0)
            ajv = *(const f16x4*)&xjsh[(jc * 64 + wv * 16 + lm) * 4];
#pragma unroll
        for (int it = 0; it < 4; ++it) {
            f32x4 z; z[0] = 0.f; z[1] = 0.f; z[2] = 0.f; z[3] = 0.f;
            f32x4 cg = __builtin_amdgcn_mfma_f32_16x16x16f16(ajv, bi[it], z, 0, 0, 0);
            f16x4 dv;
#pragma unroll
            for (int r = 0; r < 4; ++r)
                dv[r] = (f16)__builtin_amdgcn_sqrtf(fmaxf(cg[r], 0.f));
            int row = it * 16 + lm;
            int colstart = wv * 16 + q * 4;
            int addr = row * 64 + (((colstart & ~7) ^ ((row & 7) << 3)) | (colstart & 7));
            *(f16x4*)&Dsh[buf][addr] = dv;
        }
    };

    f32x4 acc[4][2];   // [mt][nt2] : 64 i x 32 h
    auto zero_acc = [&]() {
#pragma unroll
        for (int mt = 0; mt < 4; ++mt)
#pragma unroll
            for (int n2 = 0; n2 < 2; ++n2)
#pragma unroll
                for (int e = 0; e < 4; ++e) acc[mt][n2][e] = 0.f;
    };
    zero_acc();

    // ---- prologue: D chunk 0 + B chunk 0 prefetch ----
    f16x8 bfbuf[2][2][2];   // [parity][nt2][ks]
    {
        const f16* wb = img2 + (size_t)(0 * 2 + half) * 4096 + lane * 8;
#pragma unroll
        for (int n2 = 0; n2 < 2; ++n2)
#pragma unroll
            for (int ks = 0; ks < 2; ++ks)
                bfbuf[0][n2][ks] = *(const f16x8*)(wb + (((nbase + n2) * 2 + ks)) * 512);
    }
    dotstore(0, 0);
    __syncthreads();

    // ---- layer-0 K-loop: B consumed one full iteration after issue ----
#pragma unroll
    for (int jc = 0; jc < 16; ++jc) {
        const int cur = jc & 1, nxt = cur ^ 1;
        if (jc < 15) {
            const f16* wb = img2 + (size_t)((jc + 1) * 2 + half) * 4096 + lane * 8;
#pragma unroll
            for (int n2 = 0; n2 < 2; ++n2)
#pragma unroll
                for (int ks = 0; ks < 2; ++ks)
                    bfbuf[nxt][n2][ks] = *(const f16x8*)(wb + (((nbase + n2) * 2 + ks)) * 512);
        }
        f16x8 af[4][2];
#pragma unroll
        for (int mt = 0; mt < 4; ++mt)
#pragma unroll
            for (int ks = 0; ks < 2; ++ks) {
                int row = mt * 16 + lm;
                int col = ks * 32 + q * 8;
                af[mt][ks] = *(const f16x8*)(Dsh[cur] + row * 64 + (col ^ ((row & 7) << 3)));
            }
        if (jc < 15) dotstore(jc + 1, nxt);
#pragma unroll
        for (int ks = 0; ks < 2; ++ks)
#pragma unroll
            for (int mt = 0; mt < 4; ++mt)
#pragma unroll
                for (int n2 = 0; n2 < 2; ++n2)
                    acc[mt][n2] = __builtin_amdgcn_mfma_f32_16x16x32_f16(
                        af[mt][ks], bfbuf[cur][n2][ks], acc[mt][n2], 0, 0, 0);
        __syncthreads();
    }

    // hoist layer-1 B loads (chunks 16,17) above the epilogue stores
    f16x8 bL[2][4];   // [nt2][ks 0..3], k = ks*32+q*8+s
#pragma unroll
    for (int n2 = 0; n2 < 2; ++n2)
#pragma unroll
        for (int ks = 0; ks < 4; ++ks) {
            const f16* wb = img2 + (size_t)((16 + (ks >> 1)) * 2 + half) * 4096 + lane * 8;
            bL[n2][ks] = *(const f16x8*)(wb + (((nbase + n2) * 2 + (ks & 1))) * 512);
        }

    // ---- epilogue 0: h0 = leaky(acc + bias + norm*w8) -> Hh[64][128] swizzled ----
    // lane holds C[i = mt*16+q*4+r][h = wv*32 + n2*16 + lm]
#pragma unroll
    for (int mt = 0; mt < 4; ++mt)
#pragma unroll
        for (int n2 = 0; n2 < 2; ++n2) {
            const int h = wv * 32 + n2 * 16 + lm;
            const float bh = biass[h], w8h = w8s[h];
#pragma unroll
            for (int r = 0; r < 4; ++r) {
                int i = mt * 16 + q * 4 + r;
                float val = acc[mt][n2][r] + bh + normv[i] * w8h;
                val = val > 0.f ? val : 0.01f * val;
                int addr = i * 128 + (((h & ~7) ^ ((i & 7) << 3)) | (h & 7));
                Hh[addr] = (f16)val;
            }
        }
    __syncthreads();

    // ---- layer 1: A = h0 rows from Hh (K=128), B = bL ----
    zero_acc();
    {
        f16x8 af[4][4];
#pragma unroll
        for (int mt = 0; mt < 4; ++mt)
#pragma unroll
            for (int ks = 0; ks < 4; ++ks) {
                int row = mt * 16 + lm;
                int col = ks * 32 + q * 8;
                af[mt][ks] = *(const f16x8*)(Hh + row * 128 + (col ^ ((row & 7) << 3)));
            }
#pragma unroll
        for (int ks = 0; ks < 4; ++ks)
#pragma unroll
            for (int mt = 0; mt < 4; ++mt)
#pragma unroll
                for (int n2 = 0; n2 < 2; ++n2)
                    acc[mt][n2] = __builtin_amdgcn_mfma_f32_16x16x32_f16(
                        af[mt][ks], bL[n2][ks], acc[mt][n2], 0, 0, 0);
    }

    // hoist layer-2 B loads (chunks 18,19)
    f16x8 bM[2][4];
#pragma unroll
    for (int n2 = 0; n2 < 2; ++n2)
#pragma unroll
        for (int ks = 0; ks < 4; ++ks) {
            const f16* wb = img2 + (size_t)((18 + (ks >> 1)) * 2 + half) * 4096 + lane * 8;
            bM[n2][ks] = *(const f16x8*)(wb + (((nbase + n2) * 2 + (ks & 1))) * 512);
        }
    __syncthreads();

    // ---- epilogue 1: h1 = leaky(acc + b1) -> Hh ----
#pragma unroll
    for (int mt = 0; mt < 4; ++mt)
#pragma unroll
        for (int n2 = 0; n2 < 2; ++n2) {
            const int h = wv * 32 + n2 * 16 + lm;
            const float bh = b1p[h];
#pragma unroll
            for (int r = 0; r < 4; ++r) {
                int i = mt * 16 + q * 4 + r;
                float val = acc[mt][n2][r] + bh;
                val = val > 0.f ? val : 0.01f * val;
                int addr = i * 128 + (((h & ~7) ^ ((i & 7) << 3)) | (h & 7));
                Hh[addr] = (f16)val;
            }
        }
    __syncthreads();

    // ---- layer 2 ----
    zero_acc();
    {
        f16x8 af[4][4];
#pragma unroll
        for (int mt = 0; mt < 4; ++mt)
#pragma unroll
            for (int ks = 0; ks < 4; ++ks) {
                int row = mt * 16 + lm;
                int col = ks * 32 + q * 8;
                af[mt][ks] = *(const f16x8*)(Hh + row * 128 + (col ^ ((row & 7) << 3)));
            }
#pragma unroll
        for (int ks = 0; ks < 4; ++ks)
#pragma unroll
            for (int mt = 0; mt < 4; ++mt)
#pragma unroll
                for (int n2 = 0; n2 < 2; ++n2)
                    acc[mt][n2] = __builtin_amdgcn_mfma_f32_16x16x32_f16(
                        af[mt][ks], bM[n2][ks], acc[mt][n2], 0, 0, 0);
    }

    // ---- contraction: out[b,o,d] += sum_i (fk+b2)*x_i / N ----
    float p[2][3];
#pragma unroll
    for (int n2 = 0; n2 < 2; ++n2)
#pragma unroll
        for (int d = 0; d < 3; ++d) p[n2][d] = 0.f;
    float bo[2];
#pragma unroll
    for (int n2 = 0; n2 < 2; ++n2) bo[n2] = b2p[wv * 32 + n2 * 16 + lm];
#pragma unroll
    for (int mt = 0; mt < 4; ++mt)
#pragma unroll
        for (int r = 0; r < 4; ++r) {
            int i = mt * 16 + q * 4 + r;
            float x0 = xi[i * 4], x1 = xi[i * 4 + 1], x2 = xi[i * 4 + 2];
#pragma unroll
            for (int n2 = 0; n2 < 2; ++n2) {
                float fkv = acc[mt][n2][r] + bo[n2];
                p[n2][0] = fmaf(fkv, x0, p[n2][0]);
                p[n2][1] = fmaf(fkv, x1, p[n2][1]);
                p[n2][2] = fmaf(fkv, x2, p[n2][2]);
            }
        }
#pragma unroll
    for (int n2 = 0; n2 < 2; ++n2)
#pragma unroll
        for (int d = 0; d < 3; ++d) {
            float s = p[n2][d];
            s += __shfl_xor(s, 16);
            s += __shfl_xor(s, 32);
            if (q == 0) {
                int o = wv * 32 + n2 * 16 + lm;
                atomicAdd(&outp[(b * 128 + o) * 3 + d], s * (1.0f / 1024.0f));
            }
        }
}

extern "C" void kernel_launch(void* const* d_in, const int* in_sizes, int n_in,
                              void* d_out, int out_size, void* d_ws, size_t ws_size,
                              hipStream_t stream) {
    const float* x  = (const float*)d_in[0];
    const float* u  = (const float*)d_in[1];
    const float* W0 = (const float*)d_in[2];
    const float* b0 = (const float*)d_in[3];
    const float* W1 = (const float*)d_in[4];
    const float* b1 = (const float*)d_in[5];
    const float* W2 = (const float*)d_in[6];
    const float* b2 = (const float*)d_in[7];

    char* ws = (char*)d_ws;
    f16*   img2  = (f16*)(ws + IMG2_OFF);
    float* w8v   = (float*)(ws + W8_OFF);
    float* bias0 = (float*)(ws + BIAS0_OFF);
    float* out   = (float*)d_out;

    prep_kernel<<<189, 256, 0, stream>>>(u, W0, b0, W1, W2, img2, w8v, bias0, out);
    fused_kernel<<<512, 256, 0, stream>>>(x, b1, b2, img2, w8v, bias0, out);
}